// Round 18
// baseline (147.160 us; speedup 1.0000x reference)
//
#include <hip/hip_runtime.h>
#include <hip/hip_bf16.h>
#include <cstdint>
#include <cstddef>

#define BB 64
#define PP 16384
#define CC 81
#define NOBJ 32

// 4-byte-aligned float4: score rows are 324B apart (324 % 16 == 4).
typedef float f4u __attribute__((ext_vector_type(4), aligned(4)));

#define SB0() __builtin_amdgcn_sched_barrier(0)

// Issue 6 aligned dwordx4 loads (one 96-float window), NO waitcnt inside:
// completion is managed by the counted VMWAIT pipeline below.
#define ISSUE6(P, W0, W1, W2, W3, W4, W5)                               \
    asm volatile(                                                       \
        "global_load_dwordx4 %0, %6, off\n\t"                           \
        "global_load_dwordx4 %1, %6, off offset:64\n\t"                 \
        "global_load_dwordx4 %2, %6, off offset:128\n\t"                \
        "global_load_dwordx4 %3, %6, off offset:192\n\t"                \
        "global_load_dwordx4 %4, %6, off offset:256\n\t"                \
        "global_load_dwordx4 %5, %6, off offset:320"                    \
        : "=&v"(W0), "=&v"(W1), "=&v"(W2), "=&v"(W3), "=&v"(W4),        \
          "=&v"(W5)                                                     \
        : "v"(P));                                                      \
    SB0()

#define VMWAIT(N)                                                      \
    asm volatile("s_waitcnt vmcnt(" #N ")");                            \
    SB0()

#define PICK4(W, j) (((j) & 2) ? (((j) & 1) ? (W).w : (W).z)            \
                               : (((j) & 1) ? (W).y : (W).x))

#define ACCC(W, K)                                                     \
    { int t0 = 4 * rl - q + 16 * (K);                                   \
      e0 += ((unsigned)(t0 + 0) < 81u) ? __expf((W).x) : 0.f;           \
      e1 += ((unsigned)(t0 + 1) < 81u) ? __expf((W).y) : 0.f;           \
      e2 += ((unsigned)(t0 + 2) < 81u) ? __expf((W).z) : 0.f;           \
      e3 += ((unsigned)(t0 + 3) < 81u) ? __expf((W).w) : 0.f; }

// Pure-register pass compute: logsumexp over the window + label logit
// extracted from the loaded registers (no memory ops at all).
#define CE_COMPUTE(W0, W1, W2, W3, W4, W5, PPI, CEV, LABR)              \
    {                                                                   \
        int lr_ = (PPI) * 16 + q;                                       \
        int lab_r = __shfl(lab, lr_);                                   \
        LABR = lab_r;                                                   \
        float e0 = 0.f, e1 = 0.f, e2 = 0.f, e3 = 0.f;                   \
        ACCC(W0, 0) ACCC(W1, 1) ACCC(W2, 2)                             \
        ACCC(W3, 3) ACCC(W4, 4) ACCC(W5, 5)                             \
        float e = (e0 + e1) + (e2 + e3);                                \
        int wlab = q + lab_r;         /* window index 0..95 */          \
        int j_ = wlab & 3;                                              \
        int k_ = wlab >> 4;                                             \
        int own_ = (wlab >> 2) & 3;                                     \
        float c0_ = PICK4(W0, j_), c1_ = PICK4(W1, j_);                 \
        float c2_ = PICK4(W2, j_), c3_ = PICK4(W3, j_);                 \
        float c4_ = PICK4(W4, j_), c5_ = PICK4(W5, j_);                 \
        float cc_ = (k_ == 0) ? c0_ : (k_ == 1) ? c1_ : (k_ == 2) ? c2_ \
                  : (k_ == 3) ? c3_ : (k_ == 4) ? c4_ : c5_;            \
        float sb_ = (own_ == rl) ? cc_ : 0.f;                           \
        e  += __shfl_xor(e, 1);   e  += __shfl_xor(e, 2);               \
        sb_ += __shfl_xor(sb_, 1); sb_ += __shfl_xor(sb_, 2);           \
        CEV = __logf(e) - sb_;                                          \
    }

// ---------------- workspace layout (bytes) ----------------
// [0      , 8192   )  prior_for_obj int [B][NO]
// [8192   , 8448   )  n_pos int [B]
// [8448   , 8472   )  acc double[3] (zeroed, unused)
// [8472   , 8476   )  done counter int
// [8480   , 41248  )  partial_loc double[4096]   (one per matchce block)
// [41248  , 43296  )  batch_res double[64][4]: {conf_pos, loc, conf_neg, n_pos}
// [49152  , 180224 )  partial_pos double[16384]  (one per matchce wave)
// [196608 , 4390912)  ce_neg float [B][P]

// K1: per-(object,batch) argmax over priors + workspace init by block (0,0).
// (2048 blocks = 8 blocks/CU; round 16 showed the traffic-reduced 256-block
// variant loses 2x to occupancy — priors are L2-resident, re-reads free.)
__global__ __launch_bounds__(256) void argmax_init_kernel(
        const float* __restrict__ boxes,
        const float* __restrict__ priors,
        int* __restrict__ pfo,
        int* __restrict__ n_pos,
        double* __restrict__ acc,
        int* __restrict__ done) {
    int o = blockIdx.x;   // 0..NOBJ-1
    int b = blockIdx.y;   // 0..BB-1
    int tid = threadIdx.x;

    if (o == 0 && b == 0) {           // init (consumed only by later kernels)
        if (tid < BB) n_pos[tid] = 0;
        if (tid >= 64 && tid < 67) acc[tid - 64] = 0.0;
        if (tid == 67) *done = 0;
    }

    float4 bx = ((const float4*)boxes)[b * NOBJ + o];
    float a0 = bx.x, a1 = bx.y, a2 = bx.z, a3 = bx.w;
    float areaA = (a2 - a0) * (a3 - a1);

    float bestv = -1.f;
    int besti = 0;
    for (int i = 0; i < PP / 256; ++i) {   // 64 iterations
        int p = i * 256 + tid;
        float4 pc = ((const float4*)priors)[p];
        float px1 = pc.x - pc.z * 0.5f, py1 = pc.y - pc.w * 0.5f;
        float px2 = pc.x + pc.z * 0.5f, py2 = pc.y + pc.w * 0.5f;
        float lx = fmaxf(a0, px1), ly = fmaxf(a1, py1);
        float hx = fminf(a2, px2), hy = fminf(a3, py2);
        float iw = fmaxf(hx - lx, 0.f), ih = fmaxf(hy - ly, 0.f);
        float inter = iw * ih;
        float areaB = (px2 - px1) * (py2 - py1);
        float v = inter / (areaA + areaB - inter);
        if (v > bestv) { bestv = v; besti = p; }   // p increasing -> first occurrence
    }
    for (int off = 32; off; off >>= 1) {
        float v2 = __shfl_down(bestv, off);
        int   i2 = __shfl_down(besti, off);
        if (v2 > bestv || (v2 == bestv && i2 < besti)) { bestv = v2; besti = i2; }
    }
    __shared__ float sV[4];
    __shared__ int   sI[4];
    int lane = tid & 63, wid = tid >> 6;
    if (lane == 0) { sV[wid] = bestv; sI[wid] = besti; }
    __syncthreads();
    if (tid == 0) {
        float v = sV[0]; int ix = sI[0];
        for (int w = 1; w < 4; ++w) {
            if (sV[w] > v || (sV[w] == v && sI[w] < ix)) { v = sV[w]; ix = sI[w]; }
        }
        pfo[b * NOBJ + o] = ix;
    }
}

// K2: FUSED match + cross-entropy. CE counted-vmcnt pipeline DEPTH 3 (was 2):
// three buffer sets, 18 loads in flight through the first two computes
// (768B -> 1152B in flight per SIMD at 4 waves; the in-flight-bytes model
// says ~2.3KB/SIMD is needed to saturate HBM at ~900cy latency).
__global__ __launch_bounds__(256, 4) void matchce_kernel(
        const float* __restrict__ predicted_locs,
        const float* __restrict__ scores,
        const float* __restrict__ boxes,
        const int* __restrict__ labels,
        const float* __restrict__ priors,
        const int* __restrict__ pfo,
        int* __restrict__ n_pos,
        double* __restrict__ partial_loc,
        double* __restrict__ partial_pos,
        float* __restrict__ ce_neg) {
    __shared__ float sB[NOBJ * 4];
    __shared__ int sL[NOBJ];
    __shared__ int sP[NOBJ];
    __shared__ float sLs[4];
    __shared__ int sCs[4];

    int b = blockIdx.y;
    int tid = threadIdx.x;
    int p = blockIdx.x * 256 + tid;
    if (tid < NOBJ * 4) sB[tid] = boxes[b * NOBJ * 4 + tid];
    if (tid < NOBJ) { sL[tid] = labels[b * NOBJ + tid]; sP[tid] = pfo[b * NOBJ + tid]; }
    __syncthreads();

    // ---- match phase: thread <-> prior p ----
    float4 pc = ((const float4*)priors)[p];
    float px1 = pc.x - pc.z * 0.5f, py1 = pc.y - pc.w * 0.5f;
    float px2 = pc.x + pc.z * 0.5f, py2 = pc.y + pc.w * 0.5f;

    float bestv = -1.f; int besto = 0;
#pragma unroll
    for (int o = 0; o < NOBJ; ++o) {
        float lx = fmaxf(sB[o * 4], px1), ly = fmaxf(sB[o * 4 + 1], py1);
        float hx = fminf(sB[o * 4 + 2], px2), hy = fminf(sB[o * 4 + 3], py2);
        float iw = fmaxf(hx - lx, 0.f), ih = fmaxf(hy - ly, 0.f);
        float inter = iw * ih;
        float areaA = (sB[o * 4 + 2] - sB[o * 4]) * (sB[o * 4 + 3] - sB[o * 4 + 1]);
        float areaB = (px2 - px1) * (py2 - py1);
        float v = inter / (areaA + areaB - inter);
        if (v > bestv) { bestv = v; besto = o; }
    }
#pragma unroll
    for (int o = NOBJ - 1; o >= 0; --o) {   // forced assignment: last object wins
        if (sP[o] == p) { besto = o; bestv = 1.0f; break; }
    }
    int lab = (bestv < 0.5f) ? 0 : sL[besto];

    float l1 = 0.f;
    bool pos = (lab != 0);
    if (pos) {
        float bx0 = sB[besto * 4], bx1 = sB[besto * 4 + 1];
        float bx2 = sB[besto * 4 + 2], bx3 = sB[besto * 4 + 3];
        float cx = (bx0 + bx2) * 0.5f, cy = (bx1 + bx3) * 0.5f;
        float w = bx2 - bx0, h = bx3 - bx1;
        float g0 = (cx - pc.x) / (pc.z / 10.0f);
        float g1 = (cy - pc.y) / (pc.w / 10.0f);
        float g2 = __logf(w / pc.z) * 5.0f;
        float g3 = __logf(h / pc.w) * 5.0f;
        float4 pl = ((const float4*)predicted_locs)[(size_t)b * PP + p];
        l1 = fabsf(pl.x - g0) + fabsf(pl.y - g1) + fabsf(pl.z - g2) + fabsf(pl.w - g3);
    }

    int lane = tid & 63, wv = tid >> 6;
    float l1r = l1;
    for (int off = 32; off; off >>= 1) l1r += __shfl_down(l1r, off);
    unsigned long long bal = __ballot(pos);
    if (lane == 0) { sLs[wv] = l1r; sCs[wv] = __popcll(bal); }
    __syncthreads();
    if (tid == 0) {
        float Lr = sLs[0] + sLs[1] + sLs[2] + sLs[3];
        int cnt = sCs[0] + sCs[1] + sCs[2] + sCs[3];
        partial_loc[b * 64 + blockIdx.x] = (double)Lr;   // plain store, no atomic
        if (cnt) atomicAdd(&n_pos[b], cnt);              // int, 64 addrs: cheap
        // wave 0's two stale vmem ops are oldest in queue; the first counted
        // drain (vmcnt(12), 20 outstanding) sweeps them together with pass0,
        // leaving exactly passes 1,2 in flight — counting stays exact.
    }

    // ---- ce phase: counted-vmcnt pipelined quad-per-row, DEPTH 3 ----
    int q = lane >> 2, rl = lane & 3;
    size_t rowbase = (size_t)b * PP + blockIdx.x * 256 + wv * 64;

    const float* rp0 = scores + (rowbase + 0  + q) * CC;
    const float* rp1 = scores + (rowbase + 16 + q) * CC;
    const float* rp2 = scores + (rowbase + 32 + q) * CC;
    const float* rp3 = scores + (rowbase + 48 + q) * CC;
    // row mod 16 == q -> rp - q is a 64B-aligned window base (validated r14)
    const float* pl0 = (rp0 - q) + 4 * rl;
    const float* pl1 = (rp1 - q) + 4 * rl;
    const float* pl2 = (rp2 - q) + 4 * rl;
    const float* pl3 = (rp3 - q) + 4 * rl;

    f4u A0, A1, A2, A3, A4, A5;
    f4u B0, B1, B2, B3, B4, B5;
    f4u C0, C1, C2, C3, C4, C5;
    float cev0, cev1, cev2, cev3;
    int lb0, lb1, lb2, lb3;

    ISSUE6(pl0, A0, A1, A2, A3, A4, A5);
    ISSUE6(pl1, B0, B1, B2, B3, B4, B5);
    ISSUE6(pl2, C0, C1, C2, C3, C4, C5);
    VMWAIT(12);                                  // pass0 ready; 1,2 in flight
    CE_COMPUTE(A0, A1, A2, A3, A4, A5, 0, cev0, lb0);
    ISSUE6(pl3, A0, A1, A2, A3, A4, A5);         // recycle A: 18 in flight again
    VMWAIT(12);                                  // pass1 ready; 2,3 in flight
    CE_COMPUTE(B0, B1, B2, B3, B4, B5, 1, cev1, lb1);
    VMWAIT(6);                                   // pass2 ready; 3 in flight
    CE_COMPUTE(C0, C1, C2, C3, C4, C5, 2, cev2, lb2);
    VMWAIT(0);                                   // final drain
    CE_COMPUTE(A0, A1, A2, A3, A4, A5, 3, cev3, lb3);

    // deferred stores (after final drain: no vmem perturbed the counting)
    double accpos = 0.0;
    if (rl == 0) {
        bool p0_ = (lb0 != 0), p1_ = (lb1 != 0), p2_ = (lb2 != 0), p3_ = (lb3 != 0);
        ce_neg[rowbase + 0  + q] = p0_ ? 0.f : cev0;
        ce_neg[rowbase + 16 + q] = p1_ ? 0.f : cev1;
        ce_neg[rowbase + 32 + q] = p2_ ? 0.f : cev2;
        ce_neg[rowbase + 48 + q] = p3_ ? 0.f : cev3;
        if (p0_) accpos += (double)cev0;
        if (p1_) accpos += (double)cev1;
        if (p2_) accpos += (double)cev2;
        if (p3_) accpos += (double)cev3;
    }
    for (int off = 32; off; off >>= 1) accpos += __shfl_down(accpos, off);
    if (lane == 0)
        partial_pos[((size_t)b * 64 + blockIdx.x) * 4 + wv] = accpos;  // plain store
}

// K3: per-batch top-K of ce_neg at 512 threads; each block also reduces ITS
// batch's partial_pos/partial_loc/n_pos to one double4; ticket-winner sums
// the 64 double4s (validated rounds 13-17, byte-identical).
__global__ __launch_bounds__(512, 1) void mine_final_kernel(
        const float* __restrict__ ce_neg,
        const int* __restrict__ n_pos,
        const double* __restrict__ partial_loc,
        const double* __restrict__ partial_pos,
        double* __restrict__ batch_res,    // [64][4]
        int* __restrict__ done,
        float* __restrict__ out) {
    int b = blockIdx.x;
    int tid = threadIdx.x;
    int lane = tid & 63, wid = tid >> 6;   // 8 waves
    const float* row = ce_neg + (size_t)b * PP;

    float vals[32];
#pragma unroll
    for (int i = 0; i < 32; ++i) vals[i] = row[tid + i * 512];

    // per-batch sums of partials (256 + 64 entries)
    double sp = (tid < 256) ? partial_pos[b * 256 + tid] : 0.0;
    double sl = (tid < 64) ? partial_loc[b * 64 + tid] : 0.0;
    __shared__ double sD[8], sE[8];
    for (int off = 32; off; off >>= 1) {
        sp += __shfl_down(sp, off);
        sl += __shfl_down(sl, off);
    }
    if (lane == 0) { sD[wid] = sp; sE[wid] = sl; }

    int K = 3 * n_pos[b];
    if (K > PP) K = PP;
    __shared__ int sC[8];
    __shared__ float sS[8];

    double cn = 0.0;
    if (K > 0) {                      // block-uniform branch
        unsigned lo = 0u, hi = 0xFFFFFFFFu;
        while (lo < hi) {             // <=32 iterations, uniform control flow
            unsigned mid = (unsigned)(((unsigned long long)lo + (unsigned long long)hi + 1ull) >> 1);
            int c = 0;
#pragma unroll
            for (int i = 0; i < 32; ++i) c += (__float_as_uint(vals[i]) >= mid) ? 1 : 0;
            for (int off = 32; off; off >>= 1) c += __shfl_down(c, off);
            if (lane == 0) sC[wid] = c;
            __syncthreads();
            int ctot = sC[0] + sC[1] + sC[2] + sC[3] + sC[4] + sC[5] + sC[6] + sC[7];
            __syncthreads();
            if (ctot >= K) lo = mid; else hi = mid - 1;
        }
        float x = __uint_as_float(lo);   // K-th largest value
        int cgt = 0; float sgt = 0.f;
#pragma unroll
        for (int i = 0; i < 32; ++i) {
            if (__float_as_uint(vals[i]) > lo) { cgt++; sgt += vals[i]; }
        }
        for (int off = 32; off; off >>= 1) {
            cgt += __shfl_down(cgt, off);
            sgt += __shfl_down(sgt, off);
        }
        if (lane == 0) { sC[wid] = cgt; sS[wid] = sgt; }
        __syncthreads();
        if (tid == 0) {
            int cg = sC[0] + sC[1] + sC[2] + sC[3] + sC[4] + sC[5] + sC[6] + sC[7];
            float sg = sS[0] + sS[1] + sS[2] + sS[3] + sS[4] + sS[5] + sS[6] + sS[7];
            cn = (double)sg + (double)(K - cg) * (double)x;
        }
    }

    if (tid == 0) {
        double cp = sD[0] + sD[1] + sD[2] + sD[3] + sD[4] + sD[5] + sD[6] + sD[7];
        double lc = sE[0] + sE[1] + sE[2] + sE[3] + sE[4] + sE[5] + sE[6] + sE[7];
        batch_res[b * 4 + 0] = cp;
        batch_res[b * 4 + 1] = lc;
        batch_res[b * 4 + 2] = cn;
        batch_res[b * 4 + 3] = (double)n_pos[b];
    }

    // ticket: last block sums the 64 batch double4s and writes the scalar
    __threadfence();
    __shared__ int ticket;
    if (tid == 0) ticket = atomicAdd(done, 1);
    __syncthreads();
    if (ticket == BB - 1) {
        double cp = 0.0, lc = 0.0, cn2 = 0.0, np = 0.0;
        if (tid < BB) {
            cp  = batch_res[tid * 4 + 0];
            lc  = batch_res[tid * 4 + 1];
            cn2 = batch_res[tid * 4 + 2];
            np  = batch_res[tid * 4 + 3];
        }
        for (int off = 32; off; off >>= 1) {
            cp += __shfl_down(cp, off);
            lc += __shfl_down(lc, off);
            cn2 += __shfl_down(cn2, off);
            np += __shfl_down(np, off);
        }
        if (tid == 0) {
            double tp = np;
            out[0] = (float)((cp + cn2) / tp + lc / (tp * 4.0));
        }
    }
}

extern "C" void kernel_launch(void* const* d_in, const int* in_sizes, int n_in,
                              void* d_out, int out_size, void* d_ws, size_t ws_size,
                              hipStream_t stream) {
    const float* predicted_locs = (const float*)d_in[0];
    const float* scores         = (const float*)d_in[1];
    const float* boxes          = (const float*)d_in[2];
    const int*   labels         = (const int*)d_in[3];
    const float* priors         = (const float*)d_in[4];
    float* out = (float*)d_out;

    char* ws = (char*)d_ws;
    int*    pfo         = (int*)(ws + 0);
    int*    n_pos       = (int*)(ws + 8192);
    double* acc         = (double*)(ws + 8448);
    int*    done        = (int*)(ws + 8472);
    double* partial_loc = (double*)(ws + 8480);
    double* batch_res   = (double*)(ws + 41248);
    double* partial_pos = (double*)(ws + 49152);
    float*  ce_neg      = (float*)(ws + 196608);

    hipLaunchKernelGGL(argmax_init_kernel, dim3(NOBJ, BB), dim3(256), 0, stream,
                       boxes, priors, pfo, n_pos, acc, done);
    hipLaunchKernelGGL(matchce_kernel, dim3(PP / 256, BB), dim3(256), 0, stream,
                       predicted_locs, scores, boxes, labels, priors, pfo,
                       n_pos, partial_loc, partial_pos, ce_neg);
    hipLaunchKernelGGL(mine_final_kernel, dim3(BB), dim3(512), 0, stream,
                       ce_neg, n_pos, partial_loc, partial_pos, batch_res, done, out);
}

// Round 19
// 144.188 us; speedup vs baseline: 1.0206x; 1.0206x over previous
//
#include <hip/hip_runtime.h>
#include <hip/hip_bf16.h>
#include <cstdint>
#include <cstddef>

#define BB 64
#define PP 16384
#define CC 81
#define NOBJ 32

// 4-byte-aligned float4: score rows are 324B apart (324 % 16 == 4).
typedef float f4u __attribute__((ext_vector_type(4), aligned(4)));

#define SB0() __builtin_amdgcn_sched_barrier(0)

// Issue 6 aligned dwordx4 loads (one 96-float window), NO waitcnt inside:
// completion is managed by the counted VMWAIT pipeline below.
#define ISSUE6(P, W0, W1, W2, W3, W4, W5)                               \
    asm volatile(                                                       \
        "global_load_dwordx4 %0, %6, off\n\t"                           \
        "global_load_dwordx4 %1, %6, off offset:64\n\t"                 \
        "global_load_dwordx4 %2, %6, off offset:128\n\t"                \
        "global_load_dwordx4 %3, %6, off offset:192\n\t"                \
        "global_load_dwordx4 %4, %6, off offset:256\n\t"                \
        "global_load_dwordx4 %5, %6, off offset:320"                    \
        : "=&v"(W0), "=&v"(W1), "=&v"(W2), "=&v"(W3), "=&v"(W4),        \
          "=&v"(W5)                                                     \
        : "v"(P));                                                      \
    SB0()

#define VMWAIT(N)                                                      \
    asm volatile("s_waitcnt vmcnt(" #N ")");                            \
    SB0()

#define PICK4(W, j) (((j) & 2) ? (((j) & 1) ? (W).w : (W).z)            \
                               : (((j) & 1) ? (W).y : (W).x))

#define ACCC(W, K)                                                     \
    { int t0 = 4 * rl - q + 16 * (K);                                   \
      e0 += ((unsigned)(t0 + 0) < 81u) ? __expf((W).x) : 0.f;           \
      e1 += ((unsigned)(t0 + 1) < 81u) ? __expf((W).y) : 0.f;           \
      e2 += ((unsigned)(t0 + 2) < 81u) ? __expf((W).z) : 0.f;           \
      e3 += ((unsigned)(t0 + 3) < 81u) ? __expf((W).w) : 0.f; }

// Pure-register pass compute: logsumexp over the window + label logit
// extracted from the loaded registers (no memory ops at all).
#define CE_COMPUTE(W0, W1, W2, W3, W4, W5, PPI, CEV, LABR)              \
    {                                                                   \
        int lr_ = (PPI) * 16 + q;                                       \
        int lab_r = __shfl(lab, lr_);                                   \
        LABR = lab_r;                                                   \
        float e0 = 0.f, e1 = 0.f, e2 = 0.f, e3 = 0.f;                   \
        ACCC(W0, 0) ACCC(W1, 1) ACCC(W2, 2)                             \
        ACCC(W3, 3) ACCC(W4, 4) ACCC(W5, 5)                             \
        float e = (e0 + e1) + (e2 + e3);                                \
        int wlab = q + lab_r;         /* window index 0..95 */          \
        int j_ = wlab & 3;                                              \
        int k_ = wlab >> 4;                                             \
        int own_ = (wlab >> 2) & 3;                                     \
        float c0_ = PICK4(W0, j_), c1_ = PICK4(W1, j_);                 \
        float c2_ = PICK4(W2, j_), c3_ = PICK4(W3, j_);                 \
        float c4_ = PICK4(W4, j_), c5_ = PICK4(W5, j_);                 \
        float cc_ = (k_ == 0) ? c0_ : (k_ == 1) ? c1_ : (k_ == 2) ? c2_ \
                  : (k_ == 3) ? c3_ : (k_ == 4) ? c4_ : c5_;            \
        float sb_ = (own_ == rl) ? cc_ : 0.f;                           \
        e  += __shfl_xor(e, 1);   e  += __shfl_xor(e, 2);               \
        sb_ += __shfl_xor(sb_, 1); sb_ += __shfl_xor(sb_, 2);           \
        CEV = __logf(e) - sb_;                                          \
    }

// ---------------- workspace layout (bytes) ----------------
// [0      , 8192   )  prior_for_obj int [B][NO]
// [8192   , 8448   )  n_pos int [B]
// [8448   , 8472   )  acc double[3] (zeroed, unused)
// [8472   , 8476   )  done counter int
// [8480   , 41248  )  partial_loc double[4096]   (one per matchce block)
// [41248  , 43296  )  batch_res double[64][4]: {conf_pos, loc, conf_neg, n_pos}
// [49152  , 180224 )  partial_pos double[16384]  (one per matchce wave)
// [196608 , 4390912)  ce_neg float [B][P]

// K1: per-(object,batch) argmax over priors + workspace init by block (0,0).
// (2048 blocks = 8 blocks/CU; round 16 showed the traffic-reduced 256-block
// variant loses 2x to occupancy — priors are L2-resident, re-reads free.)
__global__ __launch_bounds__(256) void argmax_init_kernel(
        const float* __restrict__ boxes,
        const float* __restrict__ priors,
        int* __restrict__ pfo,
        int* __restrict__ n_pos,
        double* __restrict__ acc,
        int* __restrict__ done) {
    int o = blockIdx.x;   // 0..NOBJ-1
    int b = blockIdx.y;   // 0..BB-1
    int tid = threadIdx.x;

    if (o == 0 && b == 0) {           // init (consumed only by later kernels)
        if (tid < BB) n_pos[tid] = 0;
        if (tid >= 64 && tid < 67) acc[tid - 64] = 0.0;
        if (tid == 67) *done = 0;
    }

    float4 bx = ((const float4*)boxes)[b * NOBJ + o];
    float a0 = bx.x, a1 = bx.y, a2 = bx.z, a3 = bx.w;
    float areaA = (a2 - a0) * (a3 - a1);

    float bestv = -1.f;
    int besti = 0;
    for (int i = 0; i < PP / 256; ++i) {   // 64 iterations
        int p = i * 256 + tid;
        float4 pc = ((const float4*)priors)[p];
        float px1 = pc.x - pc.z * 0.5f, py1 = pc.y - pc.w * 0.5f;
        float px2 = pc.x + pc.z * 0.5f, py2 = pc.y + pc.w * 0.5f;
        float lx = fmaxf(a0, px1), ly = fmaxf(a1, py1);
        float hx = fminf(a2, px2), hy = fminf(a3, py2);
        float iw = fmaxf(hx - lx, 0.f), ih = fmaxf(hy - ly, 0.f);
        float inter = iw * ih;
        float areaB = (px2 - px1) * (py2 - py1);
        float v = inter / (areaA + areaB - inter);
        if (v > bestv) { bestv = v; besti = p; }   // p increasing -> first occurrence
    }
    for (int off = 32; off; off >>= 1) {
        float v2 = __shfl_down(bestv, off);
        int   i2 = __shfl_down(besti, off);
        if (v2 > bestv || (v2 == bestv && i2 < besti)) { bestv = v2; besti = i2; }
    }
    __shared__ float sV[4];
    __shared__ int   sI[4];
    int lane = tid & 63, wid = tid >> 6;
    if (lane == 0) { sV[wid] = bestv; sI[wid] = besti; }
    __syncthreads();
    if (tid == 0) {
        float v = sV[0]; int ix = sI[0];
        for (int w = 1; w < 4; ++w) {
            if (sV[w] > v || (sV[w] == v && sI[w] < ix)) { v = sV[w]; ix = sI[w]; }
        }
        pfo[b * NOBJ + o] = ix;
    }
}

// K2: FUSED match + cross-entropy with counted-vmcnt pipeline, DEPTH 2
// (validated rounds 15/17 at 144-145us; depth 3 was null in round 18 —
// CE is not in-flight-limited, this is the structural floor form).
__global__ __launch_bounds__(256, 4) void matchce_kernel(
        const float* __restrict__ predicted_locs,
        const float* __restrict__ scores,
        const float* __restrict__ boxes,
        const int* __restrict__ labels,
        const float* __restrict__ priors,
        const int* __restrict__ pfo,
        int* __restrict__ n_pos,
        double* __restrict__ partial_loc,
        double* __restrict__ partial_pos,
        float* __restrict__ ce_neg) {
    __shared__ float sB[NOBJ * 4];
    __shared__ int sL[NOBJ];
    __shared__ int sP[NOBJ];
    __shared__ float sLs[4];
    __shared__ int sCs[4];

    int b = blockIdx.y;
    int tid = threadIdx.x;
    int p = blockIdx.x * 256 + tid;
    if (tid < NOBJ * 4) sB[tid] = boxes[b * NOBJ * 4 + tid];
    if (tid < NOBJ) { sL[tid] = labels[b * NOBJ + tid]; sP[tid] = pfo[b * NOBJ + tid]; }
    __syncthreads();

    // ---- match phase: thread <-> prior p ----
    float4 pc = ((const float4*)priors)[p];
    float px1 = pc.x - pc.z * 0.5f, py1 = pc.y - pc.w * 0.5f;
    float px2 = pc.x + pc.z * 0.5f, py2 = pc.y + pc.w * 0.5f;

    float bestv = -1.f; int besto = 0;
#pragma unroll
    for (int o = 0; o < NOBJ; ++o) {
        float lx = fmaxf(sB[o * 4], px1), ly = fmaxf(sB[o * 4 + 1], py1);
        float hx = fminf(sB[o * 4 + 2], px2), hy = fminf(sB[o * 4 + 3], py2);
        float iw = fmaxf(hx - lx, 0.f), ih = fmaxf(hy - ly, 0.f);
        float inter = iw * ih;
        float areaA = (sB[o * 4 + 2] - sB[o * 4]) * (sB[o * 4 + 3] - sB[o * 4 + 1]);
        float areaB = (px2 - px1) * (py2 - py1);
        float v = inter / (areaA + areaB - inter);
        if (v > bestv) { bestv = v; besto = o; }
    }
#pragma unroll
    for (int o = NOBJ - 1; o >= 0; --o) {   // forced assignment: last object wins
        if (sP[o] == p) { besto = o; bestv = 1.0f; break; }
    }
    int lab = (bestv < 0.5f) ? 0 : sL[besto];

    float l1 = 0.f;
    bool pos = (lab != 0);
    if (pos) {
        float bx0 = sB[besto * 4], bx1 = sB[besto * 4 + 1];
        float bx2 = sB[besto * 4 + 2], bx3 = sB[besto * 4 + 3];
        float cx = (bx0 + bx2) * 0.5f, cy = (bx1 + bx3) * 0.5f;
        float w = bx2 - bx0, h = bx3 - bx1;
        float g0 = (cx - pc.x) / (pc.z / 10.0f);
        float g1 = (cy - pc.y) / (pc.w / 10.0f);
        float g2 = __logf(w / pc.z) * 5.0f;
        float g3 = __logf(h / pc.w) * 5.0f;
        float4 pl = ((const float4*)predicted_locs)[(size_t)b * PP + p];
        l1 = fabsf(pl.x - g0) + fabsf(pl.y - g1) + fabsf(pl.z - g2) + fabsf(pl.w - g3);
    }

    int lane = tid & 63, wv = tid >> 6;
    float l1r = l1;
    for (int off = 32; off; off >>= 1) l1r += __shfl_down(l1r, off);
    unsigned long long bal = __ballot(pos);
    if (lane == 0) { sLs[wv] = l1r; sCs[wv] = __popcll(bal); }
    __syncthreads();
    if (tid == 0) {
        float Lr = sLs[0] + sLs[1] + sLs[2] + sLs[3];
        int cnt = sCs[0] + sCs[1] + sCs[2] + sCs[3];
        partial_loc[b * 64 + blockIdx.x] = (double)Lr;   // plain store, no atomic
        if (cnt) atomicAdd(&n_pos[b], cnt);              // int, 64 addrs: cheap
        // these stale vmem ops are oldest in queue; the first counted drain
        // below sweeps them, so the pipeline counting stays exact.
    }

    // ---- ce phase: counted-vmcnt pipelined quad-per-row ----
    int q = lane >> 2, rl = lane & 3;
    size_t rowbase = (size_t)b * PP + blockIdx.x * 256 + wv * 64;

    const float* rp0 = scores + (rowbase + 0  + q) * CC;
    const float* rp1 = scores + (rowbase + 16 + q) * CC;
    const float* rp2 = scores + (rowbase + 32 + q) * CC;
    const float* rp3 = scores + (rowbase + 48 + q) * CC;
    // row mod 16 == q -> rp - q is a 64B-aligned window base (validated r14)
    const float* pl0 = (rp0 - q) + 4 * rl;
    const float* pl1 = (rp1 - q) + 4 * rl;
    const float* pl2 = (rp2 - q) + 4 * rl;
    const float* pl3 = (rp3 - q) + 4 * rl;

    f4u A0, A1, A2, A3, A4, A5;
    f4u B0, B1, B2, B3, B4, B5;
    float cev0, cev1, cev2, cev3;
    int lb0, lb1, lb2, lb3;

    ISSUE6(pl0, A0, A1, A2, A3, A4, A5);
    ISSUE6(pl1, B0, B1, B2, B3, B4, B5);
    VMWAIT(6);                                   // pass0 ready; pass1 in flight
    CE_COMPUTE(A0, A1, A2, A3, A4, A5, 0, cev0, lb0);
    ISSUE6(pl2, A0, A1, A2, A3, A4, A5);
    VMWAIT(6);                                   // pass1 ready; pass2 in flight
    CE_COMPUTE(B0, B1, B2, B3, B4, B5, 1, cev1, lb1);
    ISSUE6(pl3, B0, B1, B2, B3, B4, B5);
    VMWAIT(6);                                   // pass2 ready; pass3 in flight
    CE_COMPUTE(A0, A1, A2, A3, A4, A5, 2, cev2, lb2);
    VMWAIT(0);                                   // final drain
    CE_COMPUTE(B0, B1, B2, B3, B4, B5, 3, cev3, lb3);

    // deferred stores (after final drain: no vmem perturbed the counting)
    double accpos = 0.0;
    if (rl == 0) {
        bool p0_ = (lb0 != 0), p1_ = (lb1 != 0), p2_ = (lb2 != 0), p3_ = (lb3 != 0);
        ce_neg[rowbase + 0  + q] = p0_ ? 0.f : cev0;
        ce_neg[rowbase + 16 + q] = p1_ ? 0.f : cev1;
        ce_neg[rowbase + 32 + q] = p2_ ? 0.f : cev2;
        ce_neg[rowbase + 48 + q] = p3_ ? 0.f : cev3;
        if (p0_) accpos += (double)cev0;
        if (p1_) accpos += (double)cev1;
        if (p2_) accpos += (double)cev2;
        if (p3_) accpos += (double)cev3;
    }
    for (int off = 32; off; off >>= 1) accpos += __shfl_down(accpos, off);
    if (lane == 0)
        partial_pos[((size_t)b * 64 + blockIdx.x) * 4 + wv] = accpos;  // plain store
}

// K3: per-batch top-K of ce_neg at 512 threads; each block also reduces ITS
// batch's partial_pos/partial_loc/n_pos to one double4; ticket-winner sums
// the 64 double4s (validated rounds 13-17, byte-identical).
__global__ __launch_bounds__(512, 1) void mine_final_kernel(
        const float* __restrict__ ce_neg,
        const int* __restrict__ n_pos,
        const double* __restrict__ partial_loc,
        const double* __restrict__ partial_pos,
        double* __restrict__ batch_res,    // [64][4]
        int* __restrict__ done,
        float* __restrict__ out) {
    int b = blockIdx.x;
    int tid = threadIdx.x;
    int lane = tid & 63, wid = tid >> 6;   // 8 waves
    const float* row = ce_neg + (size_t)b * PP;

    float vals[32];
#pragma unroll
    for (int i = 0; i < 32; ++i) vals[i] = row[tid + i * 512];

    // per-batch sums of partials (256 + 64 entries)
    double sp = (tid < 256) ? partial_pos[b * 256 + tid] : 0.0;
    double sl = (tid < 64) ? partial_loc[b * 64 + tid] : 0.0;
    __shared__ double sD[8], sE[8];
    for (int off = 32; off; off >>= 1) {
        sp += __shfl_down(sp, off);
        sl += __shfl_down(sl, off);
    }
    if (lane == 0) { sD[wid] = sp; sE[wid] = sl; }

    int K = 3 * n_pos[b];
    if (K > PP) K = PP;
    __shared__ int sC[8];
    __shared__ float sS[8];

    double cn = 0.0;
    if (K > 0) {                      // block-uniform branch
        unsigned lo = 0u, hi = 0xFFFFFFFFu;
        while (lo < hi) {             // <=32 iterations, uniform control flow
            unsigned mid = (unsigned)(((unsigned long long)lo + (unsigned long long)hi + 1ull) >> 1);
            int c = 0;
#pragma unroll
            for (int i = 0; i < 32; ++i) c += (__float_as_uint(vals[i]) >= mid) ? 1 : 0;
            for (int off = 32; off; off >>= 1) c += __shfl_down(c, off);
            if (lane == 0) sC[wid] = c;
            __syncthreads();
            int ctot = sC[0] + sC[1] + sC[2] + sC[3] + sC[4] + sC[5] + sC[6] + sC[7];
            __syncthreads();
            if (ctot >= K) lo = mid; else hi = mid - 1;
        }
        float x = __uint_as_float(lo);   // K-th largest value
        int cgt = 0; float sgt = 0.f;
#pragma unroll
        for (int i = 0; i < 32; ++i) {
            if (__float_as_uint(vals[i]) > lo) { cgt++; sgt += vals[i]; }
        }
        for (int off = 32; off; off >>= 1) {
            cgt += __shfl_down(cgt, off);
            sgt += __shfl_down(sgt, off);
        }
        if (lane == 0) { sC[wid] = cgt; sS[wid] = sgt; }
        __syncthreads();
        if (tid == 0) {
            int cg = sC[0] + sC[1] + sC[2] + sC[3] + sC[4] + sC[5] + sC[6] + sC[7];
            float sg = sS[0] + sS[1] + sS[2] + sS[3] + sS[4] + sS[5] + sS[6] + sS[7];
            cn = (double)sg + (double)(K - cg) * (double)x;
        }
    }

    if (tid == 0) {
        double cp = sD[0] + sD[1] + sD[2] + sD[3] + sD[4] + sD[5] + sD[6] + sD[7];
        double lc = sE[0] + sE[1] + sE[2] + sE[3] + sE[4] + sE[5] + sE[6] + sE[7];
        batch_res[b * 4 + 0] = cp;
        batch_res[b * 4 + 1] = lc;
        batch_res[b * 4 + 2] = cn;
        batch_res[b * 4 + 3] = (double)n_pos[b];
    }

    // ticket: last block sums the 64 batch double4s and writes the scalar
    __threadfence();
    __shared__ int ticket;
    if (tid == 0) ticket = atomicAdd(done, 1);
    __syncthreads();
    if (ticket == BB - 1) {
        double cp = 0.0, lc = 0.0, cn2 = 0.0, np = 0.0;
        if (tid < BB) {
            cp  = batch_res[tid * 4 + 0];
            lc  = batch_res[tid * 4 + 1];
            cn2 = batch_res[tid * 4 + 2];
            np  = batch_res[tid * 4 + 3];
        }
        for (int off = 32; off; off >>= 1) {
            cp += __shfl_down(cp, off);
            lc += __shfl_down(lc, off);
            cn2 += __shfl_down(cn2, off);
            np += __shfl_down(np, off);
        }
        if (tid == 0) {
            double tp = np;
            out[0] = (float)((cp + cn2) / tp + lc / (tp * 4.0));
        }
    }
}

extern "C" void kernel_launch(void* const* d_in, const int* in_sizes, int n_in,
                              void* d_out, int out_size, void* d_ws, size_t ws_size,
                              hipStream_t stream) {
    const float* predicted_locs = (const float*)d_in[0];
    const float* scores         = (const float*)d_in[1];
    const float* boxes          = (const float*)d_in[2];
    const int*   labels         = (const int*)d_in[3];
    const float* priors         = (const float*)d_in[4];
    float* out = (float*)d_out;

    char* ws = (char*)d_ws;
    int*    pfo         = (int*)(ws + 0);
    int*    n_pos       = (int*)(ws + 8192);
    double* acc         = (double*)(ws + 8448);
    int*    done        = (int*)(ws + 8472);
    double* partial_loc = (double*)(ws + 8480);
    double* batch_res   = (double*)(ws + 41248);
    double* partial_pos = (double*)(ws + 49152);
    float*  ce_neg      = (float*)(ws + 196608);

    hipLaunchKernelGGL(argmax_init_kernel, dim3(NOBJ, BB), dim3(256), 0, stream,
                       boxes, priors, pfo, n_pos, acc, done);
    hipLaunchKernelGGL(matchce_kernel, dim3(PP / 256, BB), dim3(256), 0, stream,
                       predicted_locs, scores, boxes, labels, priors, pfo,
                       n_pos, partial_loc, partial_pos, ce_neg);
    hipLaunchKernelGGL(mine_final_kernel, dim3(BB), dim3(512), 0, stream,
                       ce_neg, n_pos, partial_loc, partial_pos, batch_res, done, out);
}